// Round 14
// baseline (431.690 us; speedup 1.0000x reference)
//
#include <hip/hip_runtime.h>
#include <stdint.h>

#pragma clang fp contract(off)

#define NN 1024
#define BB 2048
#define ENS 1000
#define KK 32

#define NEGC -1.0e9f
#define PADV -1.0e10f
#define L2E 1.44269504088896341f
#define LN2 0.69314718055994531f

// ===================== XLA:CPU float32 math replicas (exact path) =====================
// exp variant for inputs provably <= 0: fminf(x, 88.37) is bit-identity there.
__device__ __forceinline__ float xla_expf_neg(float xin) {
  float x = fmaxf(xin, -88.3762626647949f);
  float fx = floorf(__builtin_fmaf(x, 1.44269504088896341f, 0.5f));
  x = __builtin_fmaf(fx, -0.693359375f, x);
  x = __builtin_fmaf(fx, 2.12194440e-4f, x);
  float z = x * x;
  float y = 1.9875691500e-4f;
  y = __builtin_fmaf(y, x, 1.3981999507e-3f);
  y = __builtin_fmaf(y, x, 8.3334519073e-3f);
  y = __builtin_fmaf(y, x, 4.1665795894e-2f);
  y = __builtin_fmaf(y, x, 1.6666665459e-1f);
  y = __builtin_fmaf(y, x, 5.0000001201e-1f);
  y = __builtin_fmaf(y, z, x);
  y = y + 1.0f;
  int n = (int)fx;
  float two_n = __int_as_float((n + 127) << 23);
  return y * two_n;
}

__device__ __forceinline__ float xla_logf(float uin) {
  int ib = __float_as_int(uin);
  float e = (float)((ib >> 23) - 126);
  float m = __int_as_float((ib & 0x007FFFFF) | 0x3F000000);
  bool lt = m < 0.707106781186547524f;
  float tmp = lt ? m : 0.0f;
  e = lt ? (e - 1.0f) : e;
  float x = m - 1.0f;
  x = x + tmp;
  float z = x * x;
  float y = 7.0376836292e-2f;
  y = __builtin_fmaf(y, x, -1.1514610310e-1f);
  y = __builtin_fmaf(y, x, 1.1676998740e-1f);
  y = __builtin_fmaf(y, x, -1.2420140846e-1f);
  y = __builtin_fmaf(y, x, 1.4249322787e-1f);
  y = __builtin_fmaf(y, x, -1.6668057665e-1f);
  y = __builtin_fmaf(y, x, 2.0000714765e-1f);
  y = __builtin_fmaf(y, x, -2.4999993993e-1f);
  y = __builtin_fmaf(y, x, 3.3333331174e-1f);
  y = y * x;
  y = y * z;
  y = __builtin_fmaf(e, -2.12194440e-4f, y);
  y = __builtin_fmaf(z, -0.5f, y);
  x = x + y;
  x = __builtin_fmaf(e, 0.693359375f, x);
  return x;
}

__device__ __forceinline__ float xla_log1pf(float x) {
  float lg = xla_logf(x + 1.0f);
  float sm = __builtin_fmaf(-0.5f, x, 1.0f) * x;
  return (fabsf(x) < 1e-4f) ? sm : lg;
}

__device__ __forceinline__ float xla_logsigmoid(float v) {
  float y = -v;
  float amax = fmaxf(y, 0.0f);
  float sp = amax + xla_log1pf(xla_expf_neg(-fabsf(y)));
  return -sp + 1e-7f;
}

// ===================== fast math (marginal path only; 2e-2 tolerance) ==============
__device__ __forceinline__ float fexp2(float x) { return __builtin_amdgcn_exp2f(x); }
__device__ __forceinline__ float flog2(float x) { return __builtin_amdgcn_logf(x); }

__device__ __forceinline__ float fast_lae(float a, float b) {
  float m = fmaxf(a, b);
  float d = -fabsf(a - b);
  float e = fexp2(d * L2E);
  return m + flog2(1.0f + e) * LN2;
}

// ===================== DPP / lane helpers =====================
template <int CTRL, int ROWM>
__device__ __forceinline__ float dppz(float x) {
  return __int_as_float(__builtin_amdgcn_update_dpp(0, __float_as_int(x), CTRL, ROWM, 0xF, false));
}

__device__ __forceinline__ float shup1(float x) { return dppz<0x138, 0xF>(x); }  // wave_shr:1

// per-half (32-lane) sum; total lands at g==31 of each half
__device__ __forceinline__ float sum_half_last(float x) {
  x += dppz<0x111, 0xF>(x);   // row_shr:1
  x += dppz<0x112, 0xF>(x);   // row_shr:2
  x += dppz<0x114, 0xF>(x);   // row_shr:4
  x += dppz<0x118, 0xF>(x);   // row_shr:8
  x += dppz<0x142, 0xA>(x);   // row_bcast15 into rows 1&3
  return x;
}

// ===================== JAX threefry2x32, key(42) =====================
__device__ __forceinline__ uint32_t rotl_(uint32_t v, int s) { return (v << s) | (v >> (32 - s)); }

__device__ __forceinline__ uint32_t threefry_fold(uint32_t x0, uint32_t x1) {
  const uint32_t ks0 = 0u;
  const uint32_t ks1 = 42u;
  const uint32_t ks2 = 0x1BD11BDAu ^ 42u;
  uint32_t v0 = x0 + ks0;
  uint32_t v1 = x1 + ks1;
#define TF_R(rr) { v0 += v1; v1 = rotl_(v1, rr); v1 ^= v0; }
  TF_R(13) TF_R(15) TF_R(26) TF_R(6)
  v0 += ks1; v1 += ks2 + 1u;
  TF_R(17) TF_R(29) TF_R(16) TF_R(24)
  v0 += ks2; v1 += ks0 + 2u;
  TF_R(13) TF_R(15) TF_R(26) TF_R(6)
  v0 += ks0; v1 += ks1 + 3u;
  TF_R(17) TF_R(29) TF_R(16) TF_R(24)
  v0 += ks1; v1 += ks2 + 4u;
  TF_R(13) TF_R(15) TF_R(26) TF_R(6)
  v0 += ks2; v1 += ks0 + 5u;
#undef TF_R
  return v0 ^ v1;
}

__device__ __forceinline__ float jax_uniform01(uint32_t m) {
  uint32_t bits = threefry_fold(0u, m);
  return __uint_as_float((bits >> 9) | 0x3F800000u) - 1.0f;
}

// ===================== mega kernel, 2 rows/block, 3 waves ==========================
// roles (rotated by blockIdx):
//  0: S+PV exact backward chain, seg 15-ph at phase ph (ckpt->LDS, bits->cmaskL);
//     phases 16,17: serial top-k samplers for rows 0,1.
//  1: phases 0-1 fast F-scan (fckpt, logZ); even phases 2..16: marg seg 17-ph.
//  2: odd phases 3..17: marg seg 17-ph. (idle otherwise)
__global__ __launch_bounds__(192) void k_mega(const float* __restrict__ scores,
                                              float* __restrict__ out,
                                              float* __restrict__ margOut) {
  __shared__ float la[2][NN];              // 8 KiB   exact logsigmoid(a)
  __shared__ float luM[2][NN];             // 8 KiB   u values; reused as marg values
  __shared__ uint32_t cmaskL[2][32][32];   // 8 KiB   [row][group][channel] bit t
  __shared__ float ckptL[2][15][32];       // 3.75 KiB S[(k+1)*64]
  __shared__ float fckptL[2][15][32];      // 3.75 KiB F[(k+1)*64]
  __shared__ uint32_t bitsL[2][32];        // 256 B
  __shared__ float logZL[2];
  int tid = threadIdx.x, w = tid >> 6, lane = tid & 63;
  int g = lane & 31, half = lane >> 5;
  int row0 = blockIdx.x * 2;
  int rol = (w + blockIdx.x) % 3;
  int lr = half;

  // ---- stage: exact logsigmoid + threefry uniforms (2 rows) ----
  #pragma unroll 1
  for (int n = tid; n < 2 * NN; n += 192) {
    int r = n >> 10, i = n & (NN - 1);
    float x = (i < ENS) ? scores[(size_t)(row0 + r) * ENS + i] : PADV;
    la[r][i] = xla_logsigmoid(x);
    luM[r][i] = jax_uniform01((uint32_t)(i * BB + row0 + r));
  }
  __syncthreads();

  float s = NEGC;    // S state (role 0)
  float Fv = NEGC;   // F state (role 1)

  #pragma unroll 1
  for (int ph = 0; ph < 18; ++ph) {
    if (rol == 0) {
      if (ph <= 15) {
        // ---- exact backward S-chain + PV bits, segment 15-ph ----
        int seg = 15 - ph;
        if (seg <= 14) ckptL[lr][seg][g] = s;   // S[(seg+1)*64]
        const float4* ap = (const float4*)&la[lr][seg * 64];
        const float4* up = (const float4*)&luM[lr][seg * 64];
        float4 av[16], uv[16];
        #pragma unroll
        for (int q = 0; q < 16; ++q) { av[q] = ap[q]; uv[q] = up[q]; }
        uint32_t cw0 = 0u, cw1 = 0u;
        #pragma unroll
        for (int t = 63; t >= 0; --t) {
          float a = ((const float*)&av[t >> 2])[t & 3];
          float u = ((const float*)&uv[t >> 2])[t & 3];
          float prev = shup1(s);
          float sh = (g == 0) ? 0.0f : prev;      // S[i+1][g]
          float tv = a + sh;                      // a + s1
          float amax = fmaxf(s, tv);
          float snew = amax + xla_log1pf(xla_expf_neg(-fabsf(s - tv)));  // S[i][g+1]
          float d = tv - snew;                    // <= 0 always
          s = snew;
          float pr = xla_expf_neg(d);             // p for channel g+1 (clip no-op)
          uint32_t b = (u < pr) ? 1u : 0u;
          if (t >= 32) cw1 |= b << (t - 32); else cw0 |= b << t;
        }
        cmaskL[lr][seg * 2][g] = cw0;
        cmaskL[lr][seg * 2 + 1][g] = cw1;
      } else {
        // ---- serial top-k sampler for row (ph-16) ----
        int lrr = ph - 16;
        int r = KK;
        #pragma unroll 1
        for (int q = 0; q < 16; ++q) {
          uint32_t mw = cmaskL[lrr][2 * q + (lane >> 5)][lane & 31];
          uint32_t w0c = 0u, w1c = 0u;
          #pragma unroll
          for (int t = 0; t < 32; ++t) {
            int rl = (r > 0) ? (r - 1) : 0;
            uint32_t wv = (uint32_t)__builtin_amdgcn_readlane((int)mw, rl);
            int inc = (int)((wv >> t) & 1u) & (int)(r > 0);
            r -= inc;
            w0c |= ((uint32_t)inc) << t;
          }
          #pragma unroll
          for (int t = 0; t < 32; ++t) {
            int rl = (r > 0) ? (r - 1) : 0;
            uint32_t wv = (uint32_t)__builtin_amdgcn_readlane((int)mw, 32 + rl);
            int inc = (int)((wv >> t) & 1u) & (int)(r > 0);
            r -= inc;
            w1c |= ((uint32_t)inc) << t;
          }
          if (lane == 0) { bitsL[lrr][2 * q] = w0c; bitsL[lrr][2 * q + 1] = w1c; }
        }
      }
    } else if (rol == 1 && ph <= 1) {
      // ---- fast forward F-scan, half the row per phase ----
      #pragma unroll 1
      for (int k = ph * 8; k < ph * 8 + 8; ++k) {
        #pragma unroll
        for (int t = 0; t < 64; ++t) {
          float prev = shup1(Fv);
          float Fj = (g == 0) ? 0.0f : prev;
          Fv = fast_lae(Fv, la[lr][k * 64 + t] + Fj);
        }
        if (k <= 14) fckptL[lr][k][g] = Fv;   // F[(k+1)*64]
      }
      if (ph == 1 && g == 31) logZL[lr] = Fv;  // F[N][32]
    } else if ((rol == 1 && ph >= 2 && (ph & 1) == 0) ||
               (rol == 2 && ph >= 3 && (ph & 1) == 1)) {
      // ---- marginal job, segment 17-ph (chases the S chain) ----
      int seg = 17 - ph;
      int base = seg * 64;
      float lz = logZL[lr];
      float sM = (seg == 15) ? NEGC : ckptL[lr][seg][g];
      float sv[64];
      #pragma unroll
      for (int t = 63; t >= 0; --t) {
        float prev = shup1(sM);
        float sh = (g == 0) ? 0.0f : prev;       // S[i+1][g]
        sv[t] = __shfl_xor(sh, 31, 64);          // lane g <- S[i+1][31-g]
        sM = fast_lae(sM, la[lr][base + t] + sh);
      }
      float Fm = (seg == 0) ? NEGC : fckptL[lr][seg - 1][g];
      #pragma unroll
      for (int t = 0; t < 64; ++t) {
        float a = la[lr][base + t];
        float prev = shup1(Fm);
        float Fj = (g == 0) ? 0.0f : prev;
        float term = fexp2((Fj + sv[t] - lz) * L2E);   // <= ~1, no max pass
        float tot = sum_half_last(term);
        if (g == 31 && (base + t) < ENS)
          luM[lr][base + t] = fexp2(a * L2E) * tot;    // marg into dead lu slot
        Fm = fast_lae(Fm, a + Fj);
      }
    }
    __syncthreads();
  }

  // ---- straight-through combine + store both outputs ----
  #pragma unroll 1
  for (int n = tid; n < 2 * NN; n += 192) {
    int r = n >> 10, i = n & (NN - 1);
    if (i < ENS) {
      float m = luM[r][i];
      float bit = (float)((bitsL[r][i >> 5] >> (i & 31)) & 1u);
      size_t gi = (size_t)(row0 + r) * ENS + i;
      out[gi] = (bit - m) + m;
      margOut[gi] = m;
    }
  }
}

extern "C" void kernel_launch(void* const* d_in, const int* in_sizes, int n_in,
                              void* d_out, int out_size, void* d_ws, size_t ws_size,
                              hipStream_t stream) {
  const float* scores = (const float*)d_in[0];
  float* outbuf = (float*)d_out;
  float* margOut = outbuf + (size_t)BB * ENS;   // marginals = out upper half
  (void)in_sizes; (void)n_in; (void)out_size; (void)d_ws; (void)ws_size;

  hipLaunchKernelGGL(k_mega, dim3(BB / 2), dim3(192), 0, stream,
                     scores, outbuf, margOut);
}